// Round 15
// baseline (292.136 us; speedup 1.0000x reference)
//
#include <hip/hip_runtime.h>
#include <hip/hip_bf16.h>

// Problem dims (AttentivePoolingNetwork)
#define BB   128
#define LQ   128
#define LA   512
#define EMBD 300
#define FILT 400
#define KW   3

#define NT   25    // n-tiles of 16 (400)
#define KC   30    // k-chunks of 32 for encode (3 emb-blocks padded to 320 each)
#define KCF  13    // k-chunks of 32 over FILT=400 (12 full + 1 zero-padded)
#define MT   64    // rows per block (encode)

typedef unsigned short u16;
typedef unsigned int   u32;
typedef __attribute__((ext_vector_type(4))) int    i32x4;
typedef __attribute__((ext_vector_type(4))) float  f32x4;
typedef __attribute__((ext_vector_type(8))) __bf16 bf16x8;

__device__ __forceinline__ u16 f2b(float f){
  u32 u = __float_as_uint(f);
  u32 r = (u + 0x7FFFu + ((u >> 16) & 1u)) >> 16;   // RNE
  return (u16)r;
}
__device__ __forceinline__ u32 encf(float f){
  u32 u = __float_as_uint(f);
  return (u & 0x80000000u) ? ~u : (u | 0x80000000u);
}
__device__ __forceinline__ float decf(u32 k){
  u32 u = (k & 0x80000000u) ? (k ^ 0x80000000u) : ~k;
  return __uint_as_float(u);
}
__device__ __forceinline__ bf16x8 bzero(){
  i32x4 z; z.x = 0; z.y = 0; z.z = 0; z.w = 0;
  return __builtin_bit_cast(bf16x8, z);
}

// Fused weight prep + zeroing of rme/cme/done (contiguous u32 region).
__global__ void k_prep(const float* __restrict__ cw, const float* __restrict__ W,
                       u32* __restrict__ wTf, u32* __restrict__ wF,
                       u32* __restrict__ zreg){
  int idx = blockIdx.x * 256 + threadIdx.x;
  const int N1 = KC * NT * 64;
  const int N2 = KCF * NT * 64;
  const int N3 = BB * (LQ + LA) + BB;   // rme ++ cme ++ done
  if (idx < N1){
    int kc  = idx / (NT * 64);
    int rem = idx - kc * (NT * 64);
    int nt  = rem >> 6;
    int lane = rem & 63;
    int n = nt * 16 + (lane & 15);
    int quad = lane >> 4;
    u32 pack[4];
    #pragma unroll
    for (int d = 0; d < 4; d++){
      u16 h[2];
      #pragma unroll
      for (int s = 0; s < 2; s++){
        int kp = kc * 32 + quad * 8 + 2 * d + s;
        int kk = kp / 320, e = kp - kk * 320;
        float v = (e < EMBD) ? cw[(size_t)n * (EMBD * KW) + e * KW + kk] : 0.f;
        h[s] = f2b(v);
      }
      pack[d] = (u32)h[0] | ((u32)h[1] << 16);
    }
    i32x4 o; o.x = pack[0]; o.y = pack[1]; o.z = pack[2]; o.w = pack[3];
    *((i32x4*)wTf + idx) = o;
  } else if (idx < N1 + N2){
    int id2 = idx - N1;
    int kc  = id2 / (NT * 64);
    int rem = id2 - kc * (NT * 64);
    int nt  = rem >> 6;
    int lane = rem & 63;
    int n = nt * 16 + (lane & 15);
    int quad = lane >> 4;
    u32 pack[4];
    #pragma unroll
    for (int d = 0; d < 4; d++){
      u16 h[2];
      #pragma unroll
      for (int s = 0; s < 2; s++){
        int k = kc * 32 + quad * 8 + 2 * d + s;
        float v = (k < FILT) ? W[(size_t)k * FILT + n] : 0.f;
        h[s] = f2b(v);
      }
      pack[d] = (u32)h[0] | ((u32)h[1] << 16);
    }
    i32x4 o; o.x = pack[0]; o.y = pack[1]; o.z = pack[2]; o.w = pack[3];
    *((i32x4*)wF + id2) = o;
  } else if (idx < N1 + N2 + N3){
    zreg[idx - N1 - N2] = 0u;      // 0 < encf(any finite); done counters = 0
  }
}

// Embed + conv1d(pad=1) as MFMA GEMM — MT=64, one shared A-tile per block.
// 512 threads / 8 waves; wave w covers nt {w, w+8, w+16} (+ nt 24 for wave 0)
// over ALL 64 rows (4 m-frags). A single-buffered (LDS), B 1-deep dbuf.
__global__ __launch_bounds__(512, 4) void k_encode_all(const int* __restrict__ qtok,
    const int* __restrict__ atok, const float* __restrict__ emb,
    const u32* __restrict__ wTf, const float* __restrict__ bias,
    u16* __restrict__ outQ, u16* __restrict__ outA){
  __shared__ u16 At[66 * 328];   // 64+2 halo rows, stride 328 (43.3 KB)

  const int tid  = threadIdx.x;
  const int w    = tid >> 6;          // 0..7
  const int lane = tid & 63;
  const int col  = lane & 15;
  const int quad = lane >> 4;
  const bool has4 = (w == 0);         // wave-uniform
  const int nA = BB * LA / MT;        // 1024
  const bool isA = ((int)blockIdx.x < nA);
  const int bi = isA ? blockIdx.x : (blockIdx.x - nA);
  const int L  = isA ? LA : LQ;
  const int* toks = isA ? atok : qtok;
  u16* out = isA ? outA : outQ;
  const int row0 = bi * MT;
  const int b    = row0 / L;
  const int l0   = row0 - b * L;

  // staging (latency-batched, shared by all 8 waves): tokens first, then emb
  int tk[10], cc[10], rws[10];
  #pragma unroll
  for (int u = 0; u < 10; u++){
    int idx = tid + 512 * u;
    tk[u] = -1; cc[u] = 0; rws[u] = 0;
    if (idx < 66 * 75){
      int r = idx / 75, c4 = idx - r * 75;
      int pos = l0 - 1 + r;
      cc[u] = c4;
      rws[u] = (r * 328 + c4 * 4) >> 1;
      if ((unsigned)pos < (unsigned)L) tk[u] = toks[b * L + pos];
    }
  }
  for (int i = tid; i < 66 * 328 / 2; i += 512) ((u32*)At)[i] = 0u;
  __syncthreads();
  {
    const float4* emb4 = (const float4*)emb;
    #pragma unroll
    for (int g = 0; g < 2; g++){
      float4 v[5];
      #pragma unroll
      for (int u = 0; u < 5; u++){
        int uu = g * 5 + u;
        if (tk[uu] >= 0) v[u] = emb4[(size_t)tk[uu] * 75 + cc[uu]];
      }
      #pragma unroll
      for (int u = 0; u < 5; u++){
        int uu = g * 5 + u;
        if (tk[uu] >= 0){
          u32 p0 = (u32)f2b(v[u].x) | ((u32)f2b(v[u].y) << 16);
          u32 p1 = (u32)f2b(v[u].z) | ((u32)f2b(v[u].w) << 16);
          ((u32*)At)[rws[uu]]     = p0;
          ((u32*)At)[rws[uu] + 1] = p1;
        }
      }
    }
  }

  f32x4 acc[4][4];   // [n-tile j][m-frag mf]
  #pragma unroll
  for (int j = 0; j < 4; j++)
    #pragma unroll
    for (int mf = 0; mf < 4; mf++)
      acc[j][mf] = (f32x4){0.f, 0.f, 0.f, 0.f};

  __syncthreads();

  const i32x4* wTfp = (const i32x4*)wTf;
  i32x4 Bb[2][4];
  {
    #pragma unroll
    for (int j = 0; j < 3; j++) Bb[0][j] = wTfp[(size_t)(w + 8 * j) * 64 + lane];
    if (has4) Bb[0][3] = wTfp[(size_t)24 * 64 + lane];
  }
  #pragma unroll
  for (int kc = 0; kc < KC; kc++){
    const int cur = kc & 1;
    if (kc + 1 < KC){
      const i32x4* s = wTfp + (size_t)(kc + 1) * (NT * 64) + lane;
      #pragma unroll
      for (int j = 0; j < 3; j++) Bb[cur ^ 1][j] = s[(w + 8 * j) * 64];
      if (has4) Bb[cur ^ 1][3] = s[24 * 64];
    }
    const int kk = kc / 10, e0 = (kc - kk * 10) * 32;
    const int ebase = e0 + quad * 8;
    bf16x8 a[4];
    #pragma unroll
    for (int mf = 0; mf < 4; mf++)
      a[mf] = __builtin_bit_cast(bf16x8, *(const i32x4*)(At + (mf * 16 + col + kk) * 328 + ebase));
    #pragma unroll
    for (int j = 0; j < 3; j++){
      bf16x8 bf = __builtin_bit_cast(bf16x8, Bb[cur][j]);
      #pragma unroll
      for (int mf = 0; mf < 4; mf++)
        acc[j][mf] = __builtin_amdgcn_mfma_f32_16x16x32_bf16(a[mf], bf, acc[j][mf], 0, 0, 0);
    }
    if (has4){
      bf16x8 bf = __builtin_bit_cast(bf16x8, Bb[cur][3]);
      #pragma unroll
      for (int mf = 0; mf < 4; mf++)
        acc[3][mf] = __builtin_amdgcn_mfma_f32_16x16x32_bf16(a[mf], bf, acc[3][mf], 0, 0, 0);
    }
  }

  // epilogue: + bias, bf16 store. C/D: col=lane&15, row=quad*4+reg.
  #pragma unroll
  for (int j = 0; j < 4; j++){
    if (j == 3 && !has4) continue;     // wave-uniform
    int n = ((j < 3) ? (w + 8 * j) : 24) * 16 + col;
    float bv = bias[n];
    #pragma unroll
    for (int mf = 0; mf < 4; mf++){
      int rbase = row0 + mf * 16 + quad * 4;
      #pragma unroll
      for (int r = 0; r < 4; r++)
        out[(size_t)(rbase + r) * FILT + n] = f2b(acc[j][mf][r] + bv);
    }
  }
}

// Fused gemmT+scores (r13-proven). grid (2 qh, BB), 512 threads.
// Phase 1: Ts[64][400] = QT[b][qh*64..][:]*W (waves split nt-halves).
// Phase 2: all 512 a per block; wave = (q-tile wq) x (a-half wh), 2 groups of 8.
__global__ __launch_bounds__(512) void k_mid(const u16* __restrict__ QT,
    const u32* __restrict__ wF, const u16* __restrict__ AT,
    u32* __restrict__ rme, u32* __restrict__ cme){
  __shared__ u16 Ts[64 * 408];       // 52.2 KB
  __shared__ float cpart[512][5];    // 10.2 KB
  const int tid  = threadIdx.x;
  const int w    = tid >> 6;         // 0..7
  const int lane = tid & 63;
  const int col  = lane & 15;
  const int quad = lane >> 4;
  const int qh   = blockIdx.x;       // q-half
  const int b    = blockIdx.y;
  const int wq   = w & 3;            // m-frag (p1) / q-tile (p2)
  const int wh   = w >> 2;           // nt-half (p1) / a-half (p2)

  // ---- phase 1: Ts = QT-tile * W ----
  {
    const int bnt = wh ? 13 : 0;
    const int cnt = wh ? 12 : 13;
    const u16* arow = QT + (size_t)(b * LQ + qh * 64 + wq * 16 + col) * FILT;
    const i32x4* wFp = (const i32x4*)wF;
    for (int ntc = 0; ntc < 3; ntc++){
      const int nleft = cnt - ntc * 5;     // 5,5,3 or 5,5,2
      f32x4 acc[5];
      #pragma unroll
      for (int j = 0; j < 5; j++) acc[j] = (f32x4){0.f, 0.f, 0.f, 0.f};
      i32x4 Ab[2], Bb[2][5];
      Ab[0] = *(const i32x4*)(arow + quad * 8);
      #pragma unroll
      for (int j = 0; j < 5; j++)
        if (j < nleft) Bb[0][j] = wFp[(size_t)(bnt + ntc * 5 + j) * 64 + lane];
      for (int kc = 0; kc < KCF; kc++){
        const int cur = kc & 1;
        if (kc + 1 < KCF){
          Ab[cur ^ 1] = *(const i32x4*)(arow + (kc + 1) * 32 + quad * 8);
          #pragma unroll
          for (int j = 0; j < 5; j++)
            if (j < nleft)
              Bb[cur ^ 1][j] = wFp[((size_t)(kc + 1) * NT + bnt + ntc * 5 + j) * 64 + lane];
        }
        bf16x8 a = __builtin_bit_cast(bf16x8, Ab[cur]);
        #pragma unroll
        for (int j = 0; j < 5; j++)
          if (j < nleft)
            acc[j] = __builtin_amdgcn_mfma_f32_16x16x32_bf16(a,
                       __builtin_bit_cast(bf16x8, Bb[cur][j]), acc[j], 0, 0, 0);
      }
      #pragma unroll
      for (int j = 0; j < 5; j++){
        if (j < nleft){
          int g = (bnt + ntc * 5 + j) * 16 + col;
          #pragma unroll
          for (int r = 0; r < 4; r++)
            Ts[(wq * 16 + quad * 4 + r) * 408 + g] = f2b(acc[j][r]);
        }
      }
    }
  }
  __syncthreads();

  // ---- phase 2: wave = q-tile wq x a-half wh; 2 groups of 8 a-tile streams ----
  float rm[4];
  #pragma unroll
  for (int r = 0; r < 4; r++) rm[r] = -3.4e38f;
  const u16* Tsrow = Ts + (wq * 16 + col) * 408;
  for (int atg = 0; atg < 2; atg++){
    f32x4 acc[8];
    #pragma unroll
    for (int i = 0; i < 8; i++) acc[i] = (f32x4){0.f, 0.f, 0.f, 0.f};
    const u16* ar = AT + (size_t)(b * LA + wh * 256 + atg * 128 + col) * FILT;
    i32x4 Ab2[2], Bb2[2][8];
    Ab2[0] = *(const i32x4*)(Tsrow + quad * 8);
    #pragma unroll
    for (int i = 0; i < 8; i++)
      Bb2[0][i] = *(const i32x4*)(ar + (size_t)(i * 16) * FILT + quad * 8);
    for (int kc = 0; kc < KCF; kc++){
      const int cur = kc & 1;
      if (kc + 1 < KCF){
        int off = (kc + 1) * 32 + quad * 8;
        Ab2[cur ^ 1] = *(const i32x4*)(Tsrow + off);
        #pragma unroll
        for (int i = 0; i < 8; i++)
          Bb2[cur ^ 1][i] = *(const i32x4*)(ar + (size_t)(i * 16) * FILT + off);
      }
      const bool live = (kc < 12) || (quad < 2);
      bf16x8 a = live ? __builtin_bit_cast(bf16x8, Ab2[cur]) : bzero();
      #pragma unroll
      for (int i = 0; i < 8; i++)
        acc[i] = __builtin_amdgcn_mfma_f32_16x16x32_bf16(a,
                   __builtin_bit_cast(bf16x8, Bb2[cur][i]), acc[i], 0, 0, 0);
    }
    #pragma unroll
    for (int i = 0; i < 8; i++){
      float cmx = fmaxf(fmaxf(acc[i][0], acc[i][1]), fmaxf(acc[i][2], acc[i][3]));
      cmx = fmaxf(cmx, __shfl_xor(cmx, 16));
      cmx = fmaxf(cmx, __shfl_xor(cmx, 32));
      if (quad == 0) cpart[wh * 256 + atg * 128 + i * 16 + col][wq] = cmx;
      #pragma unroll
      for (int r = 0; r < 4; r++) rm[r] = fmaxf(rm[r], acc[i][r]);
    }
  }
  #pragma unroll
  for (int r = 0; r < 4; r++){
    float m = rm[r];
    m = fmaxf(m, __shfl_xor(m, 1));
    m = fmaxf(m, __shfl_xor(m, 2));
    m = fmaxf(m, __shfl_xor(m, 4));
    m = fmaxf(m, __shfl_xor(m, 8));
    if (col == 0)
      atomicMax(&rme[b * LQ + qh * 64 + wq * 16 + quad * 4 + r], encf(m));
  }
  __syncthreads();
  {
    float m = cpart[tid][0];
    #pragma unroll
    for (int s = 1; s < 4; s++) m = fmaxf(m, cpart[tid][s]);
    atomicMax(&cme[b * LA + tid], encf(m));
  }
}

// Pooling with inline softmax + fused cosine (last-block pattern).
// grid (4, BB), 256 threads. Segment s: q in [32s,..), a in [128s,..).
__global__ __launch_bounds__(256) void k_poolcos(const u16* __restrict__ QT,
    const u16* __restrict__ AT, const u32* __restrict__ rme,
    const u32* __restrict__ cme, float* __restrict__ rqp, float* __restrict__ rap,
    u32* __restrict__ done, float* __restrict__ outp){
  __shared__ float sq[128];
  __shared__ float sa[512];
  __shared__ float red[4];
  __shared__ int elect;
  __shared__ float rd[4], r1[4], r2[4];
  const int s = blockIdx.x, b = blockIdx.y, tid = threadIdx.x;
  if (tid < 128) sq[tid] = tanhf(decf(rme[b * LQ + tid]));
  sa[tid]       = tanhf(decf(cme[b * LA + tid]));
  sa[tid + 256] = tanhf(decf(cme[b * LA + 256 + tid]));
  __syncthreads();
  if (tid < 64){
    float m = fmaxf(sq[tid], sq[tid + 64]);
    #pragma unroll
    for (int off = 32; off; off >>= 1) m = fmaxf(m, __shfl_down(m, off));
    if (tid == 0) red[0] = m;
  } else if (tid < 128){
    int l = tid - 64;
    float m = sa[l];
    #pragma unroll
    for (int i = 1; i < 8; i++) m = fmaxf(m, sa[l + 64 * i]);
    #pragma unroll
    for (int off = 32; off; off >>= 1) m = fmaxf(m, __shfl_down(m, off));
    if (l == 0) red[1] = m;
  }
  __syncthreads();
  if (tid < 128) sq[tid] = __expf(sq[tid] - red[0]);
  sa[tid]       = __expf(sa[tid] - red[1]);
  sa[tid + 256] = __expf(sa[tid + 256] - red[1]);
  __syncthreads();
  if (tid < 64){
    float v = sq[tid] + sq[tid + 64];
    #pragma unroll
    for (int off = 32; off; off >>= 1) v += __shfl_down(v, off);
    if (tid == 0) red[2] = v;
  } else if (tid < 128){
    int l = tid - 64;
    float v = 0.f;
    #pragma unroll
    for (int i = 0; i < 8; i++) v += sa[l + 64 * i];
    #pragma unroll
    for (int off = 32; off; off >>= 1) v += __shfl_down(v, off);
    if (l == 0) red[3] = v;
  }
  __syncthreads();
  if (tid < 128) sq[tid] *= (1.f / red[2]);
  sa[tid]       *= (1.f / red[3]);
  sa[tid + 256] *= (1.f / red[3]);
  __syncthreads();
  if (tid < FILT / 2){
    const u32* qp = (const u32*)(QT + (size_t)(b * LQ + s * 32) * FILT) + tid;
    const u32* ap = (const u32*)(AT + (size_t)(b * LA + s * 128) * FILT) + tid;
    float rq0 = 0.f, rq1 = 0.f, ra0 = 0.f, ra1 = 0.f;
    for (int q = 0; q < 32; q++){
      u32 u = qp[q * (FILT / 2)];
      float wv = sq[s * 32 + q];
      rq0 += __uint_as_float(u << 16) * wv;
      rq1 += __uint_as_float(u & 0xFFFF0000u) * wv;
    }
    for (int a = 0; a < 128; a++){
      u32 u = ap[a * (FILT / 2)];
      float wv = sa[s * 128 + a];
      ra0 += __uint_as_float(u << 16) * wv;
      ra1 += __uint_as_float(u & 0xFFFF0000u) * wv;
    }
    size_t base = ((size_t)b * 4 + s) * FILT + 2 * tid;
    rqp[base] = rq0; rqp[base + 1] = rq1;
    rap[base] = ra0; rap[base + 1] = ra1;
  }
  // release partials, then count; the 4th block of this batch reduces.
  __threadfence();
  __syncthreads();
  if (tid == 0) elect = (atomicAdd(&done[b], 1u) == 3u) ? 1 : 0;
  __syncthreads();
  if (elect){
    __threadfence();   // acquire: see other blocks' partials
    int lane = tid & 63, wv = tid >> 6;
    float d = 0.f, n1 = 0.f, n2 = 0.f;
    for (int f = tid; f < FILT; f += 256){
      size_t base = (size_t)b * 4 * FILT + f;
      float rq = rqp[base] + rqp[base + FILT] + rqp[base + 2 * FILT] + rqp[base + 3 * FILT];
      float ra = rap[base] + rap[base + FILT] + rap[base + 2 * FILT] + rap[base + 3 * FILT];
      d += rq * ra; n1 += rq * rq; n2 += ra * ra;
    }
    #pragma unroll
    for (int off = 32; off; off >>= 1){
      d  += __shfl_down(d, off);
      n1 += __shfl_down(n1, off);
      n2 += __shfl_down(n2, off);
    }
    if (lane == 0){ rd[wv] = d; r1[wv] = n1; r2[wv] = n2; }
    __syncthreads();
    if (tid == 0){
      float D  = rd[0] + rd[1] + rd[2] + rd[3];
      float N1 = r1[0] + r1[1] + r1[2] + r1[3];
      float N2 = r2[0] + r2[1] + r2[2] + r2[3];
      outp[b] = D / (fmaxf(sqrtf(N1), 1e-8f) * fmaxf(sqrtf(N2), 1e-8f));
    }
  }
}

extern "C" void kernel_launch(void* const* d_in, const int* in_sizes, int n_in,
                              void* d_out, int out_size, void* d_ws, size_t ws_size,
                              hipStream_t stream){
  const int*   qtok = (const int*)d_in[0];
  const int*   atok = (const int*)d_in[1];
  const float* emb  = (const float*)d_in[2];
  const float* cw   = (const float*)d_in[3];
  const float* cb   = (const float*)d_in[4];
  const float* W    = (const float*)d_in[5];
  float* outp = (float*)d_out;

  char* ws = (char*)d_ws;
  size_t off = 0;
  auto alloc = [&](size_t bytes) -> char* {
    char* p = ws + off;
    off = (off + bytes + 255) & ~(size_t)255;
    return p;
  };
  u32*   wTf = (u32*)alloc((size_t)KC * NT * 64 * 16);   // 768 KB
  u32*   wF  = (u32*)alloc((size_t)KCF * NT * 64 * 16);  // 333 KB
  u16*   QT  = (u16*)alloc((size_t)BB * LQ * FILT * 2);  // 13.1 MB
  u16*   AT  = (u16*)alloc((size_t)BB * LA * FILT * 2);  // 52.4 MB
  u32*   rme = (u32*)alloc((size_t)BB * LQ * 4);         // contiguous with cme, done
  u32*   cme = (u32*)alloc((size_t)BB * LA * 4);
  u32*   done= (u32*)alloc((size_t)BB * 4);
  float* rqp = (float*)alloc((size_t)BB * 4 * FILT * 4); // 819 KB
  float* rap = (float*)alloc((size_t)BB * 4 * FILT * 4); // 819 KB

  const int NPREP = KC * NT * 64 + KCF * NT * 64 + BB * (LQ + LA) + BB;
  const int nA = BB * LA / MT;   // 1024
  const int nQ = BB * LQ / MT;   // 256
  k_prep<<<dim3((NPREP + 255) / 256), 256, 0, stream>>>(cw, W, wTf, wF, rme);
  k_encode_all<<<dim3(nA + nQ), 512, 0, stream>>>(qtok, atok, emb, wTf, cb, QT, AT);
  k_mid<<<dim3(2, BB), 512, 0, stream>>>(QT, wF, AT, rme, cme);
  k_poolcos<<<dim3(4, BB), 256, 0, stream>>>(QT, AT, rme, cme, rqp, rap, done, outp);
}

// Round 16
// 230.882 us; speedup vs baseline: 1.2653x; 1.2653x over previous
//
#include <hip/hip_runtime.h>
#include <hip/hip_bf16.h>

// Problem dims (AttentivePoolingNetwork)
#define BB   128
#define LQ   128
#define LA   512
#define EMBD 300
#define FILT 400
#define KW   3

#define NT   25    // n-tiles of 16 (400)
#define KC   30    // k-chunks of 32 for encode (3 emb-blocks padded to 320 each)
#define KCF  13    // k-chunks of 32 over FILT=400 (12 full + 1 zero-padded)
#define MT   64    // rows per block (encode)

typedef unsigned short u16;
typedef unsigned int   u32;
typedef __attribute__((ext_vector_type(4))) int    i32x4;
typedef __attribute__((ext_vector_type(4))) float  f32x4;
typedef __attribute__((ext_vector_type(8))) __bf16 bf16x8;

__device__ __forceinline__ u16 f2b(float f){
  u32 u = __float_as_uint(f);
  u32 r = (u + 0x7FFFu + ((u >> 16) & 1u)) >> 16;   // RNE
  return (u16)r;
}
__device__ __forceinline__ u32 encf(float f){
  u32 u = __float_as_uint(f);
  return (u & 0x80000000u) ? ~u : (u | 0x80000000u);
}
__device__ __forceinline__ float decf(u32 k){
  u32 u = (k & 0x80000000u) ? (k ^ 0x80000000u) : ~k;
  return __uint_as_float(u);
}
__device__ __forceinline__ bf16x8 bzero(){
  i32x4 z; z.x = 0; z.y = 0; z.z = 0; z.w = 0;
  return __builtin_bit_cast(bf16x8, z);
}
__device__ __forceinline__ void unpack8(i32x4 v, float* f){
  u32 u;
  u = (u32)v.x; f[0] = __uint_as_float(u << 16); f[1] = __uint_as_float(u & 0xFFFF0000u);
  u = (u32)v.y; f[2] = __uint_as_float(u << 16); f[3] = __uint_as_float(u & 0xFFFF0000u);
  u = (u32)v.z; f[4] = __uint_as_float(u << 16); f[5] = __uint_as_float(u & 0xFFFF0000u);
  u = (u32)v.w; f[6] = __uint_as_float(u << 16); f[7] = __uint_as_float(u & 0xFFFF0000u);
}

// Fused weight prep + zeroing of rme/cme (contiguous u32 region).
__global__ void k_prep(const float* __restrict__ cw, const float* __restrict__ W,
                       u32* __restrict__ wTf, u32* __restrict__ wF,
                       u32* __restrict__ zreg){
  int idx = blockIdx.x * 256 + threadIdx.x;
  const int N1 = KC * NT * 64;
  const int N2 = KCF * NT * 64;
  const int N3 = BB * (LQ + LA);
  if (idx < N1){
    int kc  = idx / (NT * 64);
    int rem = idx - kc * (NT * 64);
    int nt  = rem >> 6;
    int lane = rem & 63;
    int n = nt * 16 + (lane & 15);
    int quad = lane >> 4;
    u32 pack[4];
    #pragma unroll
    for (int d = 0; d < 4; d++){
      u16 h[2];
      #pragma unroll
      for (int s = 0; s < 2; s++){
        int kp = kc * 32 + quad * 8 + 2 * d + s;
        int kk = kp / 320, e = kp - kk * 320;
        float v = (e < EMBD) ? cw[(size_t)n * (EMBD * KW) + e * KW + kk] : 0.f;
        h[s] = f2b(v);
      }
      pack[d] = (u32)h[0] | ((u32)h[1] << 16);
    }
    i32x4 o; o.x = pack[0]; o.y = pack[1]; o.z = pack[2]; o.w = pack[3];
    *((i32x4*)wTf + idx) = o;
  } else if (idx < N1 + N2){
    int id2 = idx - N1;
    int kc  = id2 / (NT * 64);
    int rem = id2 - kc * (NT * 64);
    int nt  = rem >> 6;
    int lane = rem & 63;
    int n = nt * 16 + (lane & 15);
    int quad = lane >> 4;
    u32 pack[4];
    #pragma unroll
    for (int d = 0; d < 4; d++){
      u16 h[2];
      #pragma unroll
      for (int s = 0; s < 2; s++){
        int k = kc * 32 + quad * 8 + 2 * d + s;
        float v = (k < FILT) ? W[(size_t)k * FILT + n] : 0.f;
        h[s] = f2b(v);
      }
      pack[d] = (u32)h[0] | ((u32)h[1] << 16);
    }
    i32x4 o; o.x = pack[0]; o.y = pack[1]; o.z = pack[2]; o.w = pack[3];
    *((i32x4*)wF + id2) = o;
  } else if (idx < N1 + N2 + N3){
    zreg[idx - N1 - N2] = 0u;      // 0 < encf(any finite)
  }
}

// Embed + conv1d(pad=1) as MFMA GEMM — MT=64, one shared A-tile per block.
// 512 threads / 8 waves; wave w covers nt {w, w+8, w+16} (+ nt 24 for wave 0)
// over ALL 64 rows (4 m-frags). A single-buffered (LDS), B 1-deep dbuf.
__global__ __launch_bounds__(512, 4) void k_encode_all(const int* __restrict__ qtok,
    const int* __restrict__ atok, const float* __restrict__ emb,
    const u32* __restrict__ wTf, const float* __restrict__ bias,
    u16* __restrict__ outQ, u16* __restrict__ outA){
  __shared__ u16 At[66 * 328];   // 64+2 halo rows, stride 328 (43.3 KB)

  const int tid  = threadIdx.x;
  const int w    = tid >> 6;          // 0..7
  const int lane = tid & 63;
  const int col  = lane & 15;
  const int quad = lane >> 4;
  const bool has4 = (w == 0);         // wave-uniform
  const int nA = BB * LA / MT;        // 1024
  const bool isA = ((int)blockIdx.x < nA);
  const int bi = isA ? blockIdx.x : (blockIdx.x - nA);
  const int L  = isA ? LA : LQ;
  const int* toks = isA ? atok : qtok;
  u16* out = isA ? outA : outQ;
  const int row0 = bi * MT;
  const int b    = row0 / L;
  const int l0   = row0 - b * L;

  // staging (latency-batched, shared by all 8 waves): tokens first, then emb
  int tk[10], cc[10], rws[10];
  #pragma unroll
  for (int u = 0; u < 10; u++){
    int idx = tid + 512 * u;
    tk[u] = -1; cc[u] = 0; rws[u] = 0;
    if (idx < 66 * 75){
      int r = idx / 75, c4 = idx - r * 75;
      int pos = l0 - 1 + r;
      cc[u] = c4;
      rws[u] = (r * 328 + c4 * 4) >> 1;
      if ((unsigned)pos < (unsigned)L) tk[u] = toks[b * L + pos];
    }
  }
  for (int i = tid; i < 66 * 328 / 2; i += 512) ((u32*)At)[i] = 0u;
  __syncthreads();
  {
    const float4* emb4 = (const float4*)emb;
    #pragma unroll
    for (int g = 0; g < 2; g++){
      float4 v[5];
      #pragma unroll
      for (int u = 0; u < 5; u++){
        int uu = g * 5 + u;
        if (tk[uu] >= 0) v[u] = emb4[(size_t)tk[uu] * 75 + cc[uu]];
      }
      #pragma unroll
      for (int u = 0; u < 5; u++){
        int uu = g * 5 + u;
        if (tk[uu] >= 0){
          u32 p0 = (u32)f2b(v[u].x) | ((u32)f2b(v[u].y) << 16);
          u32 p1 = (u32)f2b(v[u].z) | ((u32)f2b(v[u].w) << 16);
          ((u32*)At)[rws[uu]]     = p0;
          ((u32*)At)[rws[uu] + 1] = p1;
        }
      }
    }
  }

  f32x4 acc[4][4];   // [n-tile j][m-frag mf]
  #pragma unroll
  for (int j = 0; j < 4; j++)
    #pragma unroll
    for (int mf = 0; mf < 4; mf++)
      acc[j][mf] = (f32x4){0.f, 0.f, 0.f, 0.f};

  __syncthreads();

  const i32x4* wTfp = (const i32x4*)wTf;
  i32x4 Bb[2][4];
  {
    #pragma unroll
    for (int j = 0; j < 3; j++) Bb[0][j] = wTfp[(size_t)(w + 8 * j) * 64 + lane];
    if (has4) Bb[0][3] = wTfp[(size_t)24 * 64 + lane];
  }
  #pragma unroll
  for (int kc = 0; kc < KC; kc++){
    const int cur = kc & 1;
    if (kc + 1 < KC){
      const i32x4* s = wTfp + (size_t)(kc + 1) * (NT * 64) + lane;
      #pragma unroll
      for (int j = 0; j < 3; j++) Bb[cur ^ 1][j] = s[(w + 8 * j) * 64];
      if (has4) Bb[cur ^ 1][3] = s[24 * 64];
    }
    const int kk = kc / 10, e0 = (kc - kk * 10) * 32;
    const int ebase = e0 + quad * 8;
    bf16x8 a[4];
    #pragma unroll
    for (int mf = 0; mf < 4; mf++)
      a[mf] = __builtin_bit_cast(bf16x8, *(const i32x4*)(At + (mf * 16 + col + kk) * 328 + ebase));
    #pragma unroll
    for (int j = 0; j < 3; j++){
      bf16x8 bf = __builtin_bit_cast(bf16x8, Bb[cur][j]);
      #pragma unroll
      for (int mf = 0; mf < 4; mf++)
        acc[j][mf] = __builtin_amdgcn_mfma_f32_16x16x32_bf16(a[mf], bf, acc[j][mf], 0, 0, 0);
    }
    if (has4){
      bf16x8 bf = __builtin_bit_cast(bf16x8, Bb[cur][3]);
      #pragma unroll
      for (int mf = 0; mf < 4; mf++)
        acc[3][mf] = __builtin_amdgcn_mfma_f32_16x16x32_bf16(a[mf], bf, acc[3][mf], 0, 0, 0);
    }
  }

  // epilogue: + bias, bf16 store. C/D: col=lane&15, row=quad*4+reg.
  #pragma unroll
  for (int j = 0; j < 4; j++){
    if (j == 3 && !has4) continue;     // wave-uniform
    int n = ((j < 3) ? (w + 8 * j) : 24) * 16 + col;
    float bv = bias[n];
    #pragma unroll
    for (int mf = 0; mf < 4; mf++){
      int rbase = row0 + mf * 16 + quad * 4;
      #pragma unroll
      for (int r = 0; r < 4; r++)
        out[(size_t)(rbase + r) * FILT + n] = f2b(acc[j][mf][r] + bv);
    }
  }
}

// Fused gemmT+scores (r13-proven). grid (2 qh, BB), 512 threads.
__global__ __launch_bounds__(512) void k_mid(const u16* __restrict__ QT,
    const u32* __restrict__ wF, const u16* __restrict__ AT,
    u32* __restrict__ rme, u32* __restrict__ cme){
  __shared__ u16 Ts[64 * 408];       // 52.2 KB
  __shared__ float cpart[512][5];    // 10.2 KB
  const int tid  = threadIdx.x;
  const int w    = tid >> 6;         // 0..7
  const int lane = tid & 63;
  const int col  = lane & 15;
  const int quad = lane >> 4;
  const int qh   = blockIdx.x;       // q-half
  const int b    = blockIdx.y;
  const int wq   = w & 3;            // m-frag (p1) / q-tile (p2)
  const int wh   = w >> 2;           // nt-half (p1) / a-half (p2)

  // ---- phase 1: Ts = QT-tile * W ----
  {
    const int bnt = wh ? 13 : 0;
    const int cnt = wh ? 12 : 13;
    const u16* arow = QT + (size_t)(b * LQ + qh * 64 + wq * 16 + col) * FILT;
    const i32x4* wFp = (const i32x4*)wF;
    for (int ntc = 0; ntc < 3; ntc++){
      const int nleft = cnt - ntc * 5;     // 5,5,3 or 5,5,2
      f32x4 acc[5];
      #pragma unroll
      for (int j = 0; j < 5; j++) acc[j] = (f32x4){0.f, 0.f, 0.f, 0.f};
      i32x4 Ab[2], Bb[2][5];
      Ab[0] = *(const i32x4*)(arow + quad * 8);
      #pragma unroll
      for (int j = 0; j < 5; j++)
        if (j < nleft) Bb[0][j] = wFp[(size_t)(bnt + ntc * 5 + j) * 64 + lane];
      for (int kc = 0; kc < KCF; kc++){
        const int cur = kc & 1;
        if (kc + 1 < KCF){
          Ab[cur ^ 1] = *(const i32x4*)(arow + (kc + 1) * 32 + quad * 8);
          #pragma unroll
          for (int j = 0; j < 5; j++)
            if (j < nleft)
              Bb[cur ^ 1][j] = wFp[((size_t)(kc + 1) * NT + bnt + ntc * 5 + j) * 64 + lane];
        }
        bf16x8 a = __builtin_bit_cast(bf16x8, Ab[cur]);
        #pragma unroll
        for (int j = 0; j < 5; j++)
          if (j < nleft)
            acc[j] = __builtin_amdgcn_mfma_f32_16x16x32_bf16(a,
                       __builtin_bit_cast(bf16x8, Bb[cur][j]), acc[j], 0, 0, 0);
      }
      #pragma unroll
      for (int j = 0; j < 5; j++){
        if (j < nleft){
          int g = (bnt + ntc * 5 + j) * 16 + col;
          #pragma unroll
          for (int r = 0; r < 4; r++)
            Ts[(wq * 16 + quad * 4 + r) * 408 + g] = f2b(acc[j][r]);
        }
      }
    }
  }
  __syncthreads();

  // ---- phase 2: wave = q-tile wq x a-half wh; 2 groups of 8 a-tile streams ----
  float rm[4];
  #pragma unroll
  for (int r = 0; r < 4; r++) rm[r] = -3.4e38f;
  const u16* Tsrow = Ts + (wq * 16 + col) * 408;
  for (int atg = 0; atg < 2; atg++){
    f32x4 acc[8];
    #pragma unroll
    for (int i = 0; i < 8; i++) acc[i] = (f32x4){0.f, 0.f, 0.f, 0.f};
    const u16* ar = AT + (size_t)(b * LA + wh * 256 + atg * 128 + col) * FILT;
    i32x4 Ab2[2], Bb2[2][8];
    Ab2[0] = *(const i32x4*)(Tsrow + quad * 8);
    #pragma unroll
    for (int i = 0; i < 8; i++)
      Bb2[0][i] = *(const i32x4*)(ar + (size_t)(i * 16) * FILT + quad * 8);
    for (int kc = 0; kc < KCF; kc++){
      const int cur = kc & 1;
      if (kc + 1 < KCF){
        int off = (kc + 1) * 32 + quad * 8;
        Ab2[cur ^ 1] = *(const i32x4*)(Tsrow + off);
        #pragma unroll
        for (int i = 0; i < 8; i++)
          Bb2[cur ^ 1][i] = *(const i32x4*)(ar + (size_t)(i * 16) * FILT + off);
      }
      const bool live = (kc < 12) || (quad < 2);
      bf16x8 a = live ? __builtin_bit_cast(bf16x8, Ab2[cur]) : bzero();
      #pragma unroll
      for (int i = 0; i < 8; i++)
        acc[i] = __builtin_amdgcn_mfma_f32_16x16x32_bf16(a,
                   __builtin_bit_cast(bf16x8, Bb2[cur][i]), acc[i], 0, 0, 0);
    }
    #pragma unroll
    for (int i = 0; i < 8; i++){
      float cmx = fmaxf(fmaxf(acc[i][0], acc[i][1]), fmaxf(acc[i][2], acc[i][3]));
      cmx = fmaxf(cmx, __shfl_xor(cmx, 16));
      cmx = fmaxf(cmx, __shfl_xor(cmx, 32));
      if (quad == 0) cpart[wh * 256 + atg * 128 + i * 16 + col][wq] = cmx;
      #pragma unroll
      for (int r = 0; r < 4; r++) rm[r] = fmaxf(rm[r], acc[i][r]);
    }
  }
  #pragma unroll
  for (int r = 0; r < 4; r++){
    float m = rm[r];
    m = fmaxf(m, __shfl_xor(m, 1));
    m = fmaxf(m, __shfl_xor(m, 2));
    m = fmaxf(m, __shfl_xor(m, 4));
    m = fmaxf(m, __shfl_xor(m, 8));
    if (col == 0)
      atomicMax(&rme[b * LQ + qh * 64 + wq * 16 + quad * 4 + r], encf(m));
  }
  __syncthreads();
  {
    float m = cpart[tid][0];
    #pragma unroll
    for (int s = 1; s < 4; s++) m = fmaxf(m, cpart[tid][s]);
    atomicMax(&cme[b * LA + tid], encf(m));
  }
}

// Pooling, restructured: 512 threads, thread = (filter-group fg of 8 filters
// via one 16B load per row, row-group rg splitting rows 10 ways). Loads per
// thread <= 17 (vs 160 scalar before). Inline softmax; LDS tree-reduce.
// grid (4, BB). Segment s: q in [32s, 32s+32), a in [128s, 128s+128).
__global__ __launch_bounds__(512) void k_pool(const u16* __restrict__ QT,
    const u16* __restrict__ AT, const u32* __restrict__ rme,
    const u32* __restrict__ cme, float* __restrict__ rqp, float* __restrict__ rap){
  __shared__ float sq[128];
  __shared__ float sa[512];
  __shared__ float red[4];
  __shared__ float pq[10][400];
  __shared__ float pa[10][400];
  const int s = blockIdx.x, b = blockIdx.y, tid = threadIdx.x;
  const int w = tid >> 6, lane = tid & 63;
  if (tid < 128) sq[tid] = tanhf(decf(rme[b * LQ + tid]));
  sa[tid] = tanhf(decf(cme[b * LA + tid]));
  __syncthreads();
  if (w == 0){
    float m = fmaxf(sq[lane], sq[lane + 64]);
    #pragma unroll
    for (int off = 32; off; off >>= 1) m = fmaxf(m, __shfl_down(m, off));
    if (lane == 0) red[0] = m;
  } else if (w == 1){
    float m = sa[lane];
    #pragma unroll
    for (int i = 1; i < 8; i++) m = fmaxf(m, sa[lane + 64 * i]);
    #pragma unroll
    for (int off = 32; off; off >>= 1) m = fmaxf(m, __shfl_down(m, off));
    if (lane == 0) red[1] = m;
  }
  __syncthreads();
  if (tid < 128) sq[tid] = __expf(sq[tid] - red[0]);
  sa[tid] = __expf(sa[tid] - red[1]);
  __syncthreads();
  if (w == 0){
    float v = sq[lane] + sq[lane + 64];
    #pragma unroll
    for (int off = 32; off; off >>= 1) v += __shfl_down(v, off);
    if (lane == 0) red[2] = v;
  } else if (w == 1){
    float v = 0.f;
    #pragma unroll
    for (int i = 0; i < 8; i++) v += sa[lane + 64 * i];
    #pragma unroll
    for (int off = 32; off; off >>= 1) v += __shfl_down(v, off);
    if (lane == 0) red[3] = v;
  }
  __syncthreads();
  if (tid < 128) sq[tid] *= (1.f / red[2]);
  sa[tid] *= (1.f / red[3]);
  __syncthreads();

  const int fg = tid % 50;     // filter group: filters [fg*8, fg*8+8)
  const int rg = tid / 50;     // row group 0..9 (tid >= 500 idle)
  if (rg < 10){
    float accq[8], acca[8];
    #pragma unroll
    for (int k = 0; k < 8; k++){ accq[k] = 0.f; acca[k] = 0.f; }
    if (rg < 8){                         // q rows: 8 groups x 4 rows = 32
      #pragma unroll
      for (int i = 0; i < 4; i++){
        int q = rg * 4 + i;
        i32x4 v = *((const i32x4*)(QT + (size_t)(b * LQ + s * 32 + q) * FILT) + fg);
        float f[8]; unpack8(v, f);
        float wv = sq[s * 32 + q];
        #pragma unroll
        for (int k = 0; k < 8; k++) accq[k] += f[k] * wv;
      }
    }
    int ia0 = rg * 13;                   // a rows: 10 groups x 13 (last 11)
    int cnt = (128 - ia0 < 13) ? (128 - ia0) : 13;
    for (int i = 0; i < cnt; i++){
      int a = ia0 + i;
      i32x4 v = *((const i32x4*)(AT + (size_t)(b * LA + s * 128 + a) * FILT) + fg);
      float f[8]; unpack8(v, f);
      float wv = sa[s * 128 + a];
      #pragma unroll
      for (int k = 0; k < 8; k++) acca[k] += f[k] * wv;
    }
    #pragma unroll
    for (int k = 0; k < 8; k++){
      pq[rg][fg * 8 + k] = accq[k];
      pa[rg][fg * 8 + k] = acca[k];
    }
  }
  __syncthreads();
  if (tid < FILT){
    float q = 0.f, a2 = 0.f;
    #pragma unroll
    for (int g = 0; g < 10; g++){ q += pq[g][tid]; a2 += pa[g][tid]; }
    size_t base = ((size_t)b * 4 + s) * FILT + tid;
    rqp[base] = q; rap[base] = a2;
  }
}

// Reduce 4 partials, cosine similarity. grid (BB), 256 threads.
__global__ __launch_bounds__(256) void k_cos(const float* __restrict__ rqp,
    const float* __restrict__ rap, float* __restrict__ outp){
  __shared__ float rd[4], r1[4], r2[4];
  int b = blockIdx.x, tid = threadIdx.x;
  int lane = tid & 63, w = tid >> 6;
  float d = 0.f, n1 = 0.f, n2 = 0.f;
  for (int f = tid; f < FILT; f += 256){
    size_t base = (size_t)b * 4 * FILT + f;
    float rq = rqp[base] + rqp[base + FILT] + rqp[base + 2 * FILT] + rqp[base + 3 * FILT];
    float ra = rap[base] + rap[base + FILT] + rap[base + 2 * FILT] + rap[base + 3 * FILT];
    d += rq * ra; n1 += rq * rq; n2 += ra * ra;
  }
  #pragma unroll
  for (int off = 32; off; off >>= 1){
    d  += __shfl_down(d, off);
    n1 += __shfl_down(n1, off);
    n2 += __shfl_down(n2, off);
  }
  if (lane == 0){ rd[w] = d; r1[w] = n1; r2[w] = n2; }
  __syncthreads();
  if (tid == 0){
    float D  = rd[0] + rd[1] + rd[2] + rd[3];
    float N1 = r1[0] + r1[1] + r1[2] + r1[3];
    float N2 = r2[0] + r2[1] + r2[2] + r2[3];
    outp[b] = D / (fmaxf(sqrtf(N1), 1e-8f) * fmaxf(sqrtf(N2), 1e-8f));
  }
}

extern "C" void kernel_launch(void* const* d_in, const int* in_sizes, int n_in,
                              void* d_out, int out_size, void* d_ws, size_t ws_size,
                              hipStream_t stream){
  const int*   qtok = (const int*)d_in[0];
  const int*   atok = (const int*)d_in[1];
  const float* emb  = (const float*)d_in[2];
  const float* cw   = (const float*)d_in[3];
  const float* cb   = (const float*)d_in[4];
  const float* W    = (const float*)d_in[5];
  float* outp = (float*)d_out;

  char* ws = (char*)d_ws;
  size_t off = 0;
  auto alloc = [&](size_t bytes) -> char* {
    char* p = ws + off;
    off = (off + bytes + 255) & ~(size_t)255;
    return p;
  };
  u32*   wTf = (u32*)alloc((size_t)KC * NT * 64 * 16);   // 768 KB
  u32*   wF  = (u32*)alloc((size_t)KCF * NT * 64 * 16);  // 333 KB
  u16*   QT  = (u16*)alloc((size_t)BB * LQ * FILT * 2);  // 13.1 MB
  u16*   AT  = (u16*)alloc((size_t)BB * LA * FILT * 2);  // 52.4 MB
  u32*   rme = (u32*)alloc((size_t)BB * LQ * 4);         // contiguous with cme
  u32*   cme = (u32*)alloc((size_t)BB * LA * 4);
  float* rqp = (float*)alloc((size_t)BB * 4 * FILT * 4); // 819 KB
  float* rap = (float*)alloc((size_t)BB * 4 * FILT * 4); // 819 KB

  const int NPREP = KC * NT * 64 + KCF * NT * 64 + BB * (LQ + LA);
  const int nA = BB * LA / MT;   // 1024
  const int nQ = BB * LQ / MT;   // 256
  k_prep<<<dim3((NPREP + 255) / 256), 256, 0, stream>>>(cw, W, wTf, wF, rme);
  k_encode_all<<<dim3(nA + nQ), 512, 0, stream>>>(qtok, atok, emb, wTf, cb, QT, AT);
  k_mid<<<dim3(2, BB), 512, 0, stream>>>(QT, wF, AT, rme, cme);
  k_pool<<<dim3(4, BB), 512, 0, stream>>>(QT, AT, rme, cme, rqp, rap);
  k_cos<<<dim3(BB), 256, 0, stream>>>(rqp, rap, outp);
}